// Round 3
// baseline (111.873 us; speedup 1.0000x reference)
//
#include <hip/hip_runtime.h>

// Entangle layer — real-part-only output (harness casts complex64 ref to f32):
// input  re,im: (B=128, Q=8, R=64, A=2, K=64) float32, 8,388,608 elems each
// output: (B, Q, 2R=128, A=2, K=64) float32 = Re(reference), 16,777,216 elems
//   X branch (rr=r0):     out[b,q,r0,  1-a,k] = c * re,            c = 2^-0.25
//   Z branch (rr=64+r0):  out[b,q,64+r0, a,k] = sgn * p * (re-im), p = 2^-0.75
//                         sgn = +1 (a=0), -1 (a=1)
// One thread per 4 consecutive k: float4 loads of re/im, two float4 stores,
// all fully coalesced. Max store index == out_size/4 - 1 (verified).

__global__ __launch_bounds__(256) void entangle_kernel(
    const float4* __restrict__ re, const float4* __restrict__ im,
    float4* __restrict__ out, int n, int nout4) {
  int tid = blockIdx.x * blockDim.x + threadIdx.x;
  if (tid >= n) return;

  constexpr float c = 0.84089641525371454303f;  // 2^-0.25
  constexpr float p = 0.59460355750136053336f;  // 2^-0.75

  float4 vr = re[tid];
  float4 vi = im[tid];

  // tid -> (bq, r0, a, k4); 16 float4 per K=64 row
  int k4    = tid & 15;
  int rest  = tid >> 4;
  int a     = rest & 1;
  int rest2 = rest >> 1;
  int r0    = rest2 & 63;
  int bq    = rest2 >> 6;      // b*8 + q, 0..1023

  // X branch: out[bq, r0, 1-a, k4] = c * re
  int xo = (((bq << 7) + r0) * 2 + (1 - a)) * 16 + k4;
  if (xo < nout4) {
    float4 xv = {c * vr.x, c * vr.y, c * vr.z, c * vr.w};
    out[xo] = xv;
  }

  // Z branch: out[bq, 64+r0, a, k4] = sgn*p*(re - im)
  float s = a ? -p : p;
  int zo = (((bq << 7) + 64 + r0) * 2 + a) * 16 + k4;
  if (zo < nout4) {
    float4 zv = {s * (vr.x - vi.x), s * (vr.y - vi.y),
                 s * (vr.z - vi.z), s * (vr.w - vi.w)};
    out[zo] = zv;
  }
}

extern "C" void kernel_launch(void* const* d_in, const int* in_sizes, int n_in,
                              void* d_out, int out_size, void* d_ws, size_t ws_size,
                              hipStream_t stream) {
  const float4* re = (const float4*)d_in[0];
  const float4* im = (const float4*)d_in[1];
  float4* out = (float4*)d_out;

  int n = in_sizes[0] / 4;        // 2,097,152 threads
  int nout4 = out_size / 4;       // 4,194,304 float4 slots
  int block = 256;
  int grid = (n + block - 1) / block;  // 8192
  entangle_kernel<<<grid, block, 0, stream>>>(re, im, out, n, nout4);
}